// Round 3
// baseline (6088.882 us; speedup 1.0000x reference)
//
#include <hip/hip_runtime.h>

// TimeLSTM persistent-scan kernel for MI355X (gfx950), round 6.
// Grid: 128 blocks x 320 threads. grp = blockIdx&3 owns batches grp*16..+15;
// member = blockIdx>>2 owns columns member*16..+15 of each gate and of W_d.
// Weights live in VGPRs as f16 MFMA B-fragments for all 1024 steps.
//
// Round-6 protocol: tag-in-data publish + delayed single-shot gather.
//  - Publish = one 8B relaxed agent atomic per (b,col): {tag=t+1 | f16 c,h}.
//    Self-validating -> NO drain barrier, NO flags, NO workspace memset.
//  - The round-4 failure (gather issued too early -> all-stale -> retry
//    storms) is fixed by filling the pre-gather window with the 8 x-MFMAs:
//    x(t+1) is staged into A_sm's x-region BEFORE B1 (region is dead there:
//    the gated phase no longer reads x; its contribution is carried in accx
//    registers), and the x-MFMA for t+1 runs right after the publish. This
//    ~400-500cy of useful work matches the producers' store one-way latency,
//    so the first gather sample lands at MALL as the data does.
//  - Retry reloads only still-stale qwords (rare). Strict ==(t+1) tag check:
//    poison 0xAAAAAAAA and stale t-1 tags can never match; 2-phase buffer.
//  - Serialized comm: ~1-1.5 MALL RT/step (was ~2.5-3 with drain+flag+gather),
//    and the post-elementwise drain barrier is deleted (2 barriers/step).
//  - Waves 0-3 gather 8/8/8/7 slices; wave 4 (no delay work) does not gather.

typedef _Float16 f16;
typedef _Float16 f16x8 __attribute__((ext_vector_type(8)));
typedef float f32x4 __attribute__((ext_vector_type(4)));

#define S_ 1024
#define IN_ 256
#define H_ 512
#define ECONST 2.718281828459045f

__device__ __forceinline__ float sigf(float x) { return 1.0f / (1.0f + __expf(-x)); }
__device__ __forceinline__ float tanh_f(float x) { return 1.0f - 2.0f / (__expf(2.0f * x) + 1.0f); }

__device__ __forceinline__ unsigned long long pack_tagged(float h, float c, unsigned int tag) {
    union { f16 f; unsigned short u; } ph, pc;
    ph.f = (f16)h; pc.f = (f16)c;
    return ((unsigned long long)tag << 32) |
           ((unsigned long long)pc.u << 16) | (unsigned long long)ph.u;
}

__launch_bounds__(320, 2)
__global__ void tlstm_scan(
    const float* __restrict__ inputs, const float* __restrict__ tstamps,
    const int* __restrict__ lens,
    const float* __restrict__ W_all, const float* __restrict__ b_all,
    const float* __restrict__ U_all, const float* __restrict__ b_u,
    const float* __restrict__ W_d, const float* __restrict__ b_d,
    float* __restrict__ out0, float* __restrict__ out1, float* __restrict__ out2,
    unsigned long long* __restrict__ hcbuf)
{
    __shared__ __align__(16) f16 A_sm[96 * 16 * 8];   // 24 KB  (h: kb0..63, x: kb64..95)
    __shared__ __align__(16) f16 C_sm[64 * 16 * 8];   // 16 KB  (c operand)
    __shared__ float outs_sm[5 * 16 * 17];            // +1 pad on col
    __shared__ float c_loc[16 * 16];                  // fp32 c state (own cells)
    __shared__ float bias_sm[5 * 16];
    __shared__ int   len_sm[16];

    const int tid    = threadIdx.x;
    const int grp    = blockIdx.x & 3;
    const int member = blockIdx.x >> 2;
    const int wave   = tid >> 6;
    const int lane   = tid & 63;
    const int q      = lane >> 4;   // quad
    const int r16    = lane & 15;   // A: m / B: n / C: col
    const int j0     = member * 16;

    // ---------- preload weights into VGPRs as B-fragments ----------
    // B[k][n]: n = lane&15, k = kk*32 + q*8 + e
    f16x8 bw[24];
    if (wave < 4) {
        const int col = wave * 512 + j0 + r16;
#pragma unroll
        for (int kk = 0; kk < 24; ++kk) {
            f16x8 v;
            const int kbase = kk * 32 + q * 8;
#pragma unroll
            for (int e = 0; e < 8; ++e) {
                const int k = kbase + e;
                const float w = (kk < 16) ? W_all[k * 2048 + col]
                                          : U_all[(k - 512) * 2048 + col];
                v[e] = (f16)w;
            }
            bw[kk] = v;
        }
    } else {
        const int col = j0 + r16;
#pragma unroll
        for (int kk = 0; kk < 16; ++kk) {
            f16x8 v;
            const int kbase = kk * 32 + q * 8;
#pragma unroll
            for (int e = 0; e < 8; ++e) v[e] = (f16)W_d[(kbase + e) * 512 + col];
            bw[kk] = v;
        }
#pragma unroll
        for (int kk = 16; kk < 24; ++kk) bw[kk] = bw[0];
    }

    // slice list: waves 0-3 gather 31 remote slices (8/8/8/7)
    int sl[8];
    int ns = 0;
    if (wave < 4)
        for (int s = wave; s < 32; s += 4)
            if (s != member) sl[ns++] = s;

    // ---------- init LDS state ----------
    {
        uint4 z; z.x = z.y = z.z = z.w = 0u;
        uint4* a4 = (uint4*)A_sm;
        uint4* c4 = (uint4*)C_sm;
        for (int i = tid; i < 1024; i += 320) { a4[i] = z; c4[i] = z; }
        if (tid < 256) c_loc[tid] = 0.0f;
        if (tid < 64) {
            const int w = tid >> 4, n = tid & 15;
            const int col = w * 512 + j0 + n;
            bias_sm[w * 16 + n] = b_all[col] + b_u[col];
        } else if (tid < 80) {
            const int n = tid & 15;
            bias_sm[64 + n] = b_d[j0 + n];
        }
        if (tid < 16) len_sm[tid] = lens[grp * 16 + tid];
        // stage x(0) into A_sm kb 64..95
        for (int idx = tid; idx < 1024; idx += 320) {
            const int b = idx >> 6;
            const int kx0 = (idx & 63) << 2;
            const float4 v = *(const float4*)&inputs[(((size_t)(grp * 16 + b)) * S_ + 0) * IN_ + kx0];
            union { f16 h[4]; uint2 u; } p;
            p.h[0] = (f16)v.x; p.h[1] = (f16)v.y; p.h[2] = (f16)v.z; p.h[3] = (f16)v.w;
            const int kb = 64 + (kx0 >> 3), e = kx0 & 7;
            *(uint2*)&A_sm[(kb * 16 + b) * 8 + e] = p.u;
        }
    }
    __syncthreads();

    // ---------- pre-loop: accx(0) from x(0) already staged in kb64..95 ----------
    f32x4 accx0 = {0.f, 0.f, 0.f, 0.f}, accx1 = {0.f, 0.f, 0.f, 0.f};
    if (wave < 4) {
        const f16* abase = &A_sm[(q * 16 + r16) * 8];
#pragma unroll
        for (int kx = 0; kx < 8; ++kx) {
            const f16x8 a = *(const f16x8*)(abase + (16 + kx) * 512);
            if (kx & 1) accx1 = __builtin_amdgcn_mfma_f32_16x16x32_f16(a, bw[16 + kx], accx1, 0, 0, 0);
            else        accx0 = __builtin_amdgcn_mfma_f32_16x16x32_f16(a, bw[16 + kx], accx0, 0, 0, 0);
        }
    }

    // per-group exchange buffer: 2 phases x 8192 qwords (64 KB per phase)
    unsigned long long* const hc_g = hcbuf + (size_t)grp * 2 * 8192;

    for (int t = 0; t < S_; ++t) {
        // ts(t) + x(t+1) loads at iteration top — complete under the MFMA phase
        float ts = 0.0f;
        float4 xv[4];
        const bool have_x = (t + 1 < S_);
        if (tid < 256) {
            const int gb = grp * 16 + (tid >> 4);
            ts = tstamps[(size_t)gb * S_ + t];
            if (have_x) {
#pragma unroll
                for (int k2 = 0; k2 < 4; ++k2) {
                    const int idx = k2 * 256 + tid;
                    const int b = idx >> 6;
                    const int kx0 = (idx & 63) << 2;
                    xv[k2] = *(const float4*)&inputs[(((size_t)(grp * 16 + b)) * S_ + (t + 1)) * IN_ + kx0];
                }
            }
        }

        // ---------- gated MFMA phase: 16 h/c-MFMAs (x carried in accx) ----------
        f32x4 acc0, acc1;
        if (wave < 4) {
            acc0 = accx0; acc1 = accx1;
            const f16* abase = &A_sm[(q * 16 + r16) * 8];
#pragma unroll
            for (int kk = 0; kk < 16; ++kk) {
                const f16x8 a = *(const f16x8*)(abase + kk * 512);
                if (kk & 1) acc1 = __builtin_amdgcn_mfma_f32_16x16x32_f16(a, bw[kk], acc1, 0, 0, 0);
                else        acc0 = __builtin_amdgcn_mfma_f32_16x16x32_f16(a, bw[kk], acc0, 0, 0, 0);
            }
        } else {
            acc0 = (f32x4){0.f, 0.f, 0.f, 0.f}; acc1 = acc0;
            const f16* abase = &C_sm[(q * 16 + r16) * 8];
#pragma unroll
            for (int kk = 0; kk < 16; ++kk) {
                const f16x8 a = *(const f16x8*)(abase + kk * 512);
                if (kk & 1) acc1 = __builtin_amdgcn_mfma_f32_16x16x32_f16(a, bw[kk], acc1, 0, 0, 0);
                else        acc0 = __builtin_amdgcn_mfma_f32_16x16x32_f16(a, bw[kk], acc0, 0, 0, 0);
            }
        }
        const f32x4 acc = acc0 + acc1;
        // C/D: col = lane&15, row = quad*4 + reg  (row = batch)
#pragma unroll
        for (int r = 0; r < 4; ++r)
            outs_sm[(wave * 16 + q * 4 + r) * 17 + r16] = acc[r];

        // stage x(t+1) into kb64..95 BEFORE B1 (region dead in gated phase;
        // read after B1 by this iteration's comm-window x-MFMA)
        if (have_x && tid < 256) {
#pragma unroll
            for (int k2 = 0; k2 < 4; ++k2) {
                const int idx = k2 * 256 + tid;
                const int b = idx >> 6;
                const int kx0 = (idx & 63) << 2;
                union { f16 h[4]; uint2 u; } p;
                p.h[0] = (f16)xv[k2].x; p.h[1] = (f16)xv[k2].y;
                p.h[2] = (f16)xv[k2].z; p.h[3] = (f16)xv[k2].w;
                const int kb = 64 + (kx0 >> 3), e = kx0 & 7;
                *(uint2*)&A_sm[(kb * 16 + b) * 8 + e] = p.u;
            }
        }
        __syncthreads();   // B1: outs_sm + x(t+1) staged; MFMA done with A/C_sm

        // ---------- elementwise + tagged publish (no drain, no flag) ----------
        if (tid < 256) {
            const int b = tid >> 4, jj = tid & 15;
            const int gb = grp * 16 + b;
            const float f  = outs_sm[(0 * 16 + b) * 17 + jj] + bias_sm[0  + jj];
            const float i_ = outs_sm[(1 * 16 + b) * 17 + jj] + bias_sm[16 + jj];
            const float o  = outs_sm[(2 * 16 + b) * 17 + jj] + bias_sm[32 + jj];
            const float ct = outs_sm[(3 * 16 + b) * 17 + jj] + bias_sm[48 + jj];
            const float d  = outs_sm[(4 * 16 + b) * 17 + jj] + bias_sm[64 + jj];
            const float gt = 1.0f / __logf(ECONST + ts);
            const float cs1   = tanh_f(d);
            const float cprev = c_loc[tid];
            const float cadj  = cprev - cs1 + cs1 * gt;
            const float cnew  = sigf(f) * cadj + sigf(i_) * tanh_f(ct);
            const float hnew  = sigf(o) * tanh_f(cnew);
            // publish FIRST — the remote critical path starts here
            __hip_atomic_store(hc_g + (size_t)(t & 1) * 8192 + member * 256 + tid,
                               pack_tagged(hnew, cnew, (unsigned int)(t + 1)),
                               __ATOMIC_RELAXED, __HIP_MEMORY_SCOPE_AGENT);
            c_loc[tid] = cnew;
            const int col = j0 + jj;
            const int len = len_sm[b];
            out0[((size_t)gb * S_ + t) * H_ + col] = (t < len) ? hnew : 0.0f;
            if (t == len - 1) {
                out1[gb * H_ + col] = hnew;
                out2[gb * H_ + col] = cnew;
            }
            // own slice straight into LDS operands (never gathered)
            const int fi = ((col >> 3) * 16 + b) * 8 + (col & 7);
            ((f16*)A_sm)[fi] = (f16)hnew;
            ((f16*)C_sm)[fi] = (f16)cnew;
        }
        // compiler fence: publish store may not sink below the gather loads
        asm volatile("" ::: "memory");

        if (t < S_ - 1) {
            // ---------- delay window: x-MFMA for t+1 (hides store one-way) ----------
            if (wave < 4) {
                const f16* abase = &A_sm[(q * 16 + r16) * 8];
                f32x4 ax0 = {0.f, 0.f, 0.f, 0.f}, ax1 = {0.f, 0.f, 0.f, 0.f};
#pragma unroll
                for (int kx = 0; kx < 8; ++kx) {
                    const f16x8 a = *(const f16x8*)(abase + (16 + kx) * 512);
                    if (kx & 1) ax1 = __builtin_amdgcn_mfma_f32_16x16x32_f16(a, bw[16 + kx], ax1, 0, 0, 0);
                    else        ax0 = __builtin_amdgcn_mfma_f32_16x16x32_f16(a, bw[16 + kx], ax0, 0, 0, 0);
                }
                accx0 = ax0; accx1 = ax1;

                // ---------- gather + validate + sparse retry ----------
                // slice layout: qword j = b*16 + c; lane owns j = 4*lane..+3
                const unsigned long long* src = hc_g + (size_t)(t & 1) * 8192;
                const unsigned int tag = (unsigned int)(t + 1);
                const int jb = lane * 4;
                unsigned long long v[8][4];
                unsigned int pend = (ns >= 8) ? 0xFFFFFFFFu : ((1u << (4 * ns)) - 1u);
                do {
#pragma unroll
                    for (int u = 0; u < 8; ++u) {
                        if (u < ns) {
                            const unsigned long long* sb = src + sl[u] * 256 + jb;
#pragma unroll
                            for (int k = 0; k < 4; ++k)
                                if ((pend >> (u * 4 + k)) & 1u)
                                    v[u][k] = __hip_atomic_load(sb + k, __ATOMIC_RELAXED,
                                                                __HIP_MEMORY_SCOPE_AGENT);
                        }
                    }
#pragma unroll
                    for (int u = 0; u < 8; ++u) {
                        if (u < ns) {
#pragma unroll
                            for (int k = 0; k < 4; ++k)
                                if (((pend >> (u * 4 + k)) & 1u) &&
                                    (unsigned int)(v[u][k] >> 32) == tag)
                                    pend &= ~(1u << (u * 4 + k));
                        }
                    }
                } while (__ballot(pend != 0u) != 0ull);

                // unpack: 4 cols per lane per slice -> one uint2 to A_sm + C_sm
                const int ub  = lane >> 2;          // batch row
                const int uc4 = (lane & 3) * 4;     // local col base (0,4,8,12)
#pragma unroll
                for (int u = 0; u < 8; ++u) {
                    if (u < ns) {
                        const int s = sl[u];
                        const unsigned int p0 = (unsigned int)v[u][0];
                        const unsigned int p1 = (unsigned int)v[u][1];
                        const unsigned int p2 = (unsigned int)v[u][2];
                        const unsigned int p3 = (unsigned int)v[u][3];
                        const int col = s * 16 + uc4;
                        const int fi  = ((col >> 3) * 16 + ub) * 8 + (col & 7);
                        uint2 hp, cp;
                        hp.x = (p0 & 0xFFFFu) | (p1 << 16);
                        hp.y = (p2 & 0xFFFFu) | (p3 << 16);
                        cp.x = (p0 >> 16) | (p1 & 0xFFFF0000u);
                        cp.y = (p2 >> 16) | (p3 & 0xFFFF0000u);
                        *(uint2*)((f16*)A_sm + fi) = hp;
                        *(uint2*)((f16*)C_sm + fi) = cp;
                    }
                }
            }
            __syncthreads();   // B2: operands for step t+1 ready
        }
    }
}

extern "C" void kernel_launch(void* const* d_in, const int* in_sizes, int n_in,
                              void* d_out, int out_size, void* d_ws, size_t ws_size,
                              hipStream_t stream) {
    const float* inputs  = (const float*)d_in[0];
    const float* tstamps = (const float*)d_in[1];
    const int*   lens    = (const int*)d_in[2];
    const float* W_all   = (const float*)d_in[3];
    const float* b_all   = (const float*)d_in[4];
    const float* U_all   = (const float*)d_in[5];
    const float* b_u     = (const float*)d_in[6];
    const float* W_d     = (const float*)d_in[7];
    const float* b_d     = (const float*)d_in[8];

    float* out0 = (float*)d_out;                    // [64,1024,512]
    float* out1 = out0 + (size_t)64 * 1024 * 512;   // last_h [64,512]
    float* out2 = out1 + (size_t)64 * 512;          // last_c [64,512]

    // exchange buffer: 4 groups x 2 phases x 8192 qwords = 512 KB.
    // No memset: tags are compared for EQUALITY with t+1 (<=1024), so the
    // 0xAA..AA poison (hi32 = 0xAAAAAAAA) and stale t-1 tags never match.
    unsigned long long* hcbuf = (unsigned long long*)d_ws;

    tlstm_scan<<<dim3(128), dim3(320), 0, stream>>>(
        inputs, tstamps, lens, W_all, b_all, U_all, b_u, W_d, b_d,
        out0, out1, out2, hcbuf);
}

// Round 4
// 3872.855 us; speedup vs baseline: 1.5722x; 1.5722x over previous
//
#include <hip/hip_runtime.h>

// TimeLSTM persistent-scan kernel for MI355X (gfx950), round 7.
// Topology change, protocol preserved. Grid: 64 blocks x 640 threads (10 waves).
// grp = blockIdx&3 owns batches grp*16..+15; member = blockIdx>>2 (0..15) owns
// columns member*32..+31 of each gate and of W_d. Weights live in VGPRs as f16
// MFMA B-fragments (24 per wave, same as round 3 -> VGPR ~128, no spill).
//
// Rationale: rounds 4-6 proved tag-in-data polling self-congests (gather
// floods MALL while publish stores try to land -> retry storms, FETCH +140MB).
// Round-3 protocol (publish -> __syncthreads vmcnt drain -> flag -> lane-
// parallel flag poll -> gather) is kept EXACTLY. This round halves the
// contention coefficient instead: fan-in 31->15 slices, blocks 128->64,
// gather traffic/step 4MB->1.9MB. Per-wave MFMA work unchanged (waves 0-7:
// gate halves; waves 8-9: W_d halves; 24/16 MFMAs per wave).

typedef _Float16 f16;
typedef _Float16 f16x8 __attribute__((ext_vector_type(8)));
typedef float f32x4 __attribute__((ext_vector_type(4)));

#define S_ 1024
#define IN_ 256
#define H_ 512
#define ECONST 2.718281828459045f

__device__ __forceinline__ float sigf(float x) { return 1.0f / (1.0f + __expf(-x)); }
__device__ __forceinline__ float tanh_f(float x) { return 1.0f - 2.0f / (__expf(2.0f * x) + 1.0f); }

__device__ __forceinline__ unsigned int pack_hc(float h, float c) {
    union { f16 f; unsigned short u; } ph, pc;
    ph.f = (f16)h; pc.f = (f16)c;
    return ((unsigned int)pc.u << 16) | (unsigned int)ph.u;
}

__launch_bounds__(640, 1)
__global__ void tlstm_scan(
    const float* __restrict__ inputs, const float* __restrict__ tstamps,
    const int* __restrict__ lens,
    const float* __restrict__ W_all, const float* __restrict__ b_all,
    const float* __restrict__ U_all, const float* __restrict__ b_u,
    const float* __restrict__ W_d, const float* __restrict__ b_d,
    float* __restrict__ out0, float* __restrict__ out1, float* __restrict__ out2,
    unsigned int* __restrict__ hcbuf, unsigned int* __restrict__ flags)
{
    __shared__ __align__(16) f16 A_sm[96 * 16 * 8];   // 24 KB  (h: kb0..63, x: kb64..95)
    __shared__ __align__(16) f16 C_sm[64 * 16 * 8];   // 16 KB  (c operand)
    __shared__ float outs_sm[5 * 16 * 33];            // 16 batches x 32 cols x 5 mats, +1 pad
    __shared__ float c_loc[16 * 32];                  // fp32 c state (own cells)
    __shared__ float bias_sm[5 * 32];
    __shared__ int   len_sm[16];

    const int tid    = threadIdx.x;
    const int grp    = blockIdx.x & 3;
    const int member = blockIdx.x >> 2;   // 0..15
    const int wave   = tid >> 6;          // 0..9
    const int lane   = tid & 63;
    const int q      = lane >> 4;   // quad
    const int r16    = lane & 15;   // A: m / B: n / C: col
    const int j0     = member * 32;

    // ---------- preload weights into VGPRs as B-fragments ----------
    // B[k][n]: n = lane&15, k = kk*32 + q*8 + e
    f16x8 bw[24];
    if (wave < 8) {
        const int col = (wave >> 1) * 512 + j0 + (wave & 1) * 16 + r16;
#pragma unroll
        for (int kk = 0; kk < 24; ++kk) {
            f16x8 v;
            const int kbase = kk * 32 + q * 8;
#pragma unroll
            for (int e = 0; e < 8; ++e) {
                const int k = kbase + e;
                const float w = (kk < 16) ? W_all[k * 2048 + col]
                                          : U_all[(k - 512) * 2048 + col];
                v[e] = (f16)w;
            }
            bw[kk] = v;
        }
    } else {
        const int col = j0 + (wave & 1) * 16 + r16;
#pragma unroll
        for (int kk = 0; kk < 16; ++kk) {
            f16x8 v;
            const int kbase = kk * 32 + q * 8;
#pragma unroll
            for (int e = 0; e < 8; ++e) v[e] = (f16)W_d[(kbase + e) * 512 + col];
            bw[kk] = v;
        }
#pragma unroll
        for (int kk = 16; kk < 24; ++kk) bw[kk] = bw[0];
    }

    // slice list for this wave: candidates {wave, wave+10} (16 slices over 10
    // waves), minus own member. ns in {0,1,2}.
    int sl[2];
    int ns = 0;
    for (int s = wave; s < 16; s += 10)
        if (s != member) sl[ns++] = s;

    // ---------- init LDS state ----------
    {
        uint4 z; z.x = z.y = z.z = z.w = 0u;
        uint4* a4 = (uint4*)A_sm;
        uint4* c4 = (uint4*)C_sm;
        for (int i = tid; i < 1024; i += 640) { a4[i] = z; c4[i] = z; }
        if (tid < 512) c_loc[tid] = 0.0f;
        if (tid < 128) {
            const int w = tid >> 5, n = tid & 31;
            const int col = w * 512 + j0 + n;
            bias_sm[tid] = b_all[col] + b_u[col];
        } else if (tid < 160) {
            bias_sm[tid] = b_d[j0 + (tid & 31)];
        }
        if (tid < 16) len_sm[tid] = lens[grp * 16 + tid];
        // stage x(0) into A_sm kb 64..95
        for (int idx = tid; idx < 1024; idx += 640) {
            const int b = idx >> 6;
            const int kx0 = (idx & 63) << 2;
            const float4 v = *(const float4*)&inputs[(((size_t)(grp * 16 + b)) * S_ + 0) * IN_ + kx0];
            union { f16 h[4]; uint2 u; } p;
            p.h[0] = (f16)v.x; p.h[1] = (f16)v.y; p.h[2] = (f16)v.z; p.h[3] = (f16)v.w;
            const int kb = 64 + (kx0 >> 3), e = kx0 & 7;
            *(uint2*)&A_sm[(kb * 16 + b) * 8 + e] = p.u;
        }
    }
    __syncthreads();

    // per-group exchange buffer: 2 phases x 8192 dwords (32 KB per phase)
    unsigned int* const hc_g = hcbuf + (size_t)grp * 2 * 8192;
    unsigned int* const flg = flags + grp * 16;

    for (int t = 0; t < S_; ++t) {
        // ts(t) prefetch — overlaps the MFMA phase below
        float ts = 0.0f;
        if (tid < 512) {
            const int gb = grp * 16 + (tid >> 5);
            ts = tstamps[(size_t)gb * S_ + t];
        }

        // ---------- MFMA phase ----------
        f32x4 acc0 = {0.f, 0.f, 0.f, 0.f}, acc1 = {0.f, 0.f, 0.f, 0.f};
        if (wave < 8) {
            const f16* abase = &A_sm[(q * 16 + r16) * 8];
#pragma unroll
            for (int kk = 0; kk < 24; ++kk) {
                const f16x8 a = *(const f16x8*)(abase + kk * 512);
                if (kk & 1) acc1 = __builtin_amdgcn_mfma_f32_16x16x32_f16(a, bw[kk], acc1, 0, 0, 0);
                else        acc0 = __builtin_amdgcn_mfma_f32_16x16x32_f16(a, bw[kk], acc0, 0, 0, 0);
            }
        } else {
            const f16* abase = &C_sm[(q * 16 + r16) * 8];
#pragma unroll
            for (int kk = 0; kk < 16; ++kk) {
                const f16x8 a = *(const f16x8*)(abase + kk * 512);
                if (kk & 1) acc1 = __builtin_amdgcn_mfma_f32_16x16x32_f16(a, bw[kk], acc1, 0, 0, 0);
                else        acc0 = __builtin_amdgcn_mfma_f32_16x16x32_f16(a, bw[kk], acc0, 0, 0, 0);
            }
        }
        const f32x4 acc = acc0 + acc1;
        // C/D: col = lane&15, row = quad*4 + reg  (row = batch)
        // outs row-block: waves 0-7 -> gate wave>>1; waves 8-9 -> block 4 (W_d)
        {
            const int grow = (wave < 8) ? (wave >> 1) : 4;
            const int ncol = (wave & 1) * 16 + r16;
#pragma unroll
            for (int r = 0; r < 4; ++r)
                outs_sm[(grow * 16 + q * 4 + r) * 33 + ncol] = acc[r];
        }
        __syncthreads();

        // ---------- elementwise gates ----------
        if (tid < 512) {
            const int b = tid >> 5, jj = tid & 31;
            const int gb = grp * 16 + b;
            const float f  = outs_sm[(0 * 16 + b) * 33 + jj] + bias_sm[0   + jj];
            const float i_ = outs_sm[(1 * 16 + b) * 33 + jj] + bias_sm[32  + jj];
            const float o  = outs_sm[(2 * 16 + b) * 33 + jj] + bias_sm[64  + jj];
            const float ct = outs_sm[(3 * 16 + b) * 33 + jj] + bias_sm[96  + jj];
            const float d  = outs_sm[(4 * 16 + b) * 33 + jj] + bias_sm[128 + jj];
            const float gt = 1.0f / __logf(ECONST + ts);
            const float cs1   = tanh_f(d);
            const float cprev = c_loc[tid];
            const float cadj  = cprev - cs1 + cs1 * gt;
            const float cnew  = sigf(f) * cadj + sigf(i_) * tanh_f(ct);
            const float hnew  = sigf(o) * tanh_f(cnew);
            c_loc[tid] = cnew;
            const int col = j0 + jj;
            const int len = len_sm[b];
            out0[((size_t)gb * S_ + t) * H_ + col] = (t < len) ? hnew : 0.0f;
            if (t == len - 1) {
                out1[gb * H_ + col] = hnew;
                out2[gb * H_ + col] = cnew;
            }
            // own slice straight into LDS operands (never gathered)
            const int fi = ((col >> 3) * 16 + b) * 8 + (col & 7);
            ((f16*)A_sm)[fi] = (f16)hnew;
            ((f16*)C_sm)[fi] = (f16)cnew;
            // publish packed (c,h): dword idx = member*512 + tid (contiguous 2KB)
            __hip_atomic_store(hc_g + (t & 1) * 8192 + member * 512 + tid,
                               pack_hc(hnew, cnew),
                               __ATOMIC_RELAXED, __HIP_MEMORY_SCOPE_AGENT);
        }
        __syncthreads();   // per-wave vmcnt(0) drain: publish stores ack'd at MALL

        if (t < S_ - 1) {
            const unsigned int tag = (unsigned int)(t + 1);
            if (tid == 0)
                __hip_atomic_store(&flg[member], tag,
                                   __ATOMIC_RELAXED, __HIP_MEMORY_SCOPE_AGENT);

            // issue x(t+1) loads now; latency hides under flag visibility
            float4 xv[2];
            if (tid < 512) {
#pragma unroll
                for (int k2 = 0; k2 < 2; ++k2) {
                    const int idx = k2 * 512 + tid;
                    const int b = idx >> 6;
                    const int kx0 = (idx & 63) << 2;
                    xv[k2] = *(const float4*)&inputs[(((size_t)(grp * 16 + b)) * S_ + (t + 1)) * IN_ + kx0];
                }
            }

            // lane-parallel flag wait for this wave's 0-2 slices
            for (;;) {
                unsigned int fl = tag;
                if (lane < ns)
                    fl = __hip_atomic_load(&flg[sl[lane]],
                                           __ATOMIC_RELAXED, __HIP_MEMORY_SCOPE_AGENT);
                if (__ballot(fl >= tag) == ~0ull) break;
            }

            // batched gather: 4 qwords per lane per slice (lane owns qwords
            // 4*lane..+3 = batch lane>>2, cols (lane&3)*8 .. +7), single wait
            const unsigned long long* src =
                (const unsigned long long*)(hc_g + (t & 1) * 8192);
            unsigned long long v[2][4];
#pragma unroll
            for (int u = 0; u < 2; ++u) {
                if (u < ns) {
                    const unsigned long long* sb = src + sl[u] * 256 + lane * 4;
#pragma unroll
                    for (int k = 0; k < 4; ++k)
                        v[u][k] = __hip_atomic_load(sb + k, __ATOMIC_RELAXED,
                                                    __HIP_MEMORY_SCOPE_AGENT);
                }
            }
            // unpack: 8 consecutive cols per lane -> one uint4 per matrix
            {
                const int ub  = lane >> 2;          // batch row
                const int uc8 = (lane & 3) * 8;     // local col base (0,8,16,24)
#pragma unroll
                for (int u = 0; u < 2; ++u) {
                    if (u < ns) {
                        const int col0 = sl[u] * 32 + uc8;
                        const int fi0  = ((col0 >> 3) * 16 + ub) * 8;  // 16B aligned
                        uint4 hp, cp;
                        {
                            const unsigned int d0 = (unsigned int)v[u][0];
                            const unsigned int d1 = (unsigned int)(v[u][0] >> 32);
                            hp.x = (d0 & 0xFFFFu) | (d1 << 16);
                            cp.x = (d0 >> 16) | (d1 & 0xFFFF0000u);
                        }
                        {
                            const unsigned int d0 = (unsigned int)v[u][1];
                            const unsigned int d1 = (unsigned int)(v[u][1] >> 32);
                            hp.y = (d0 & 0xFFFFu) | (d1 << 16);
                            cp.y = (d0 >> 16) | (d1 & 0xFFFF0000u);
                        }
                        {
                            const unsigned int d0 = (unsigned int)v[u][2];
                            const unsigned int d1 = (unsigned int)(v[u][2] >> 32);
                            hp.z = (d0 & 0xFFFFu) | (d1 << 16);
                            cp.z = (d0 >> 16) | (d1 & 0xFFFF0000u);
                        }
                        {
                            const unsigned int d0 = (unsigned int)v[u][3];
                            const unsigned int d1 = (unsigned int)(v[u][3] >> 32);
                            hp.w = (d0 & 0xFFFFu) | (d1 << 16);
                            cp.w = (d0 >> 16) | (d1 & 0xFFFF0000u);
                        }
                        *(uint4*)((f16*)A_sm + fi0) = hp;
                        *(uint4*)((f16*)C_sm + fi0) = cp;
                    }
                }
            }

            // stage x(t+1) into A_sm kb 64..95
            if (tid < 512) {
#pragma unroll
                for (int k2 = 0; k2 < 2; ++k2) {
                    const int idx = k2 * 512 + tid;
                    const int b = idx >> 6;
                    const int kx0 = (idx & 63) << 2;
                    union { f16 h[4]; uint2 u; } p;
                    p.h[0] = (f16)xv[k2].x; p.h[1] = (f16)xv[k2].y;
                    p.h[2] = (f16)xv[k2].z; p.h[3] = (f16)xv[k2].w;
                    const int kb = 64 + (kx0 >> 3), e = kx0 & 7;
                    *(uint2*)&A_sm[(kb * 16 + b) * 8 + e] = p.u;
                }
            }
            __syncthreads();   // operands for step t+1 ready
        }
    }
}

extern "C" void kernel_launch(void* const* d_in, const int* in_sizes, int n_in,
                              void* d_out, int out_size, void* d_ws, size_t ws_size,
                              hipStream_t stream) {
    const float* inputs  = (const float*)d_in[0];
    const float* tstamps = (const float*)d_in[1];
    const int*   lens    = (const int*)d_in[2];
    const float* W_all   = (const float*)d_in[3];
    const float* b_all   = (const float*)d_in[4];
    const float* U_all   = (const float*)d_in[5];
    const float* b_u     = (const float*)d_in[6];
    const float* W_d     = (const float*)d_in[7];
    const float* b_d     = (const float*)d_in[8];

    float* out0 = (float*)d_out;                    // [64,1024,512]
    float* out1 = out0 + (size_t)64 * 1024 * 512;   // last_h [64,512]
    float* out2 = out1 + (size_t)64 * 512;          // last_c [64,512]

    char* ws = (char*)d_ws;
    unsigned int* flags = (unsigned int*)ws;                 // 4 grp * 16 dwords
    unsigned int* hcbuf = (unsigned int*)(ws + 1024);        // 4 grp * 2 * 32KB = 256KB

    // flags must start at 0 every call (ws is poisoned 0xAA; >= compare)
    hipMemsetAsync(ws, 0, 1024, stream);

    tlstm_scan<<<dim3(64), dim3(640), 0, stream>>>(
        inputs, tstamps, lens, W_all, b_all, U_all, b_u, W_d, b_d,
        out0, out1, out2, hcbuf, flags);
}